// Round 8
// baseline (1109.780 us; speedup 1.0000x reference)
//
#include <hip/hip_runtime.h>

// OnsetLSTM: 2-layer LSTM, B=256, T=512, D=160, H=128, fp32 in/out.
//
// R2-R7 lesson: hipcc enforces ~65536 VGPRs per workgroup (512thr->128/thr,
// 1024thr->64/thr) regardless of launch_bounds / waves_per_eu. The full
// weight set (295KB) can never be register-resident -> every monolithic
// variant spilled to scratch and ran L2-BW-bound (~871us).
//
// New structure (cuDNN-style): the x-side of the gates has no recurrence.
//   Gx = x @ W_ih^T  -> MFMA GEMM (f16 in, f32 accum), thousands of blocks
//   recurrence keeps ONLY W_hh in regs: 64 f16-pairs/thread at 512 thr -> fits
// Per T-chunk (NC chunks chosen from ws_size):  GEMM0 -> REC0 -> GEMM1 -> REC1
// REC: 1 block/batch-row, thread=(cell c, K-chunk s of 4): 64 dot2 + DPP
// butterfly + cell update, 1 barrier/step.

typedef _Float16 f16;
typedef _Float16 f16x8 __attribute__((ext_vector_type(8)));
typedef float f32x4 __attribute__((ext_vector_type(4)));

#define B_  256
#define T_  512
#define HID 128
#define NG  512   // 4*HID gates
#define KX0 160

static __device__ __forceinline__ unsigned pack2(float a, float b) {
  union { f16 h[2]; unsigned u; } v;
  v.h[0] = (f16)a; v.h[1] = (f16)b;
  return v.u;
}

typedef _Float16 half2_t __attribute__((ext_vector_type(2)));
static __device__ __forceinline__ float dot2f(unsigned a, unsigned b, float c) {
#if __has_builtin(__builtin_amdgcn_fdot2)
  return __builtin_amdgcn_fdot2(__builtin_bit_cast(half2_t, a),
                                __builtin_bit_cast(half2_t, b), c, false);
#else
  half2_t x = __builtin_bit_cast(half2_t, a);
  half2_t y = __builtin_bit_cast(half2_t, b);
  float r = c;
  r = fmaf((float)x[0], (float)y[0], r);
  r = fmaf((float)x[1], (float)y[1], r);
  return r;
#endif
}

static __device__ __forceinline__ float fast_rcp(float x) {
#if __has_builtin(__builtin_amdgcn_rcpf)
  return __builtin_amdgcn_rcpf(x);
#else
  return 1.0f / x;
#endif
}
static __device__ __forceinline__ float fast_exp2(float x) {
#if __has_builtin(__builtin_amdgcn_exp2f)
  return __builtin_amdgcn_exp2f(x);
#else
  return exp2f(x);
#endif
}
static __device__ __forceinline__ float sigm(float x) {
  return fast_rcp(1.0f + fast_exp2(x * -1.44269504f));
}
static __device__ __forceinline__ float tanh_f(float x) {
  float e = fast_exp2(x * 2.885390082f);
  return 1.0f - 2.0f * fast_rcp(e + 1.0f);
}

template <int CTRL>
static __device__ __forceinline__ float qp_add(float v) {
  int iv = __builtin_bit_cast(int, v);
  int t = __builtin_amdgcn_update_dpp(iv, iv, CTRL, 0xF, 0xF, true);
  return v + __builtin_bit_cast(float, t);
}

// ======================= GEMM: D[M][512] = A[M][K] @ W[512][K]^T ==========
// M = B_*Tc rows. A is either f32 with (batch,t)->global-x mapping, or f16
// contiguous (the h1 chunk buffer). Tile 128x64, 256 threads = 4 waves,
// each wave 32x64 via 2x4 mfma_f32_16x16x32_f16 frags over K.
template <int K, bool AF16>
__global__ __launch_bounds__(256) void gemm_xw(
    const void* __restrict__ Aptr, size_t bStride, int tcShift, int tcMask,
    const float* __restrict__ W, f16* __restrict__ D) {
  constexpr int KP = K + 8;
  __shared__ f16 As[128][KP];
  __shared__ f16 Bs[64][KP];
  const int tid = threadIdx.x;
  const int mtile = blockIdx.x, ntile = blockIdx.y;

  if (AF16) {
    const f16* A = (const f16*)Aptr;
    for (int i = tid; i < 128 * (K / 8); i += 256) {
      int r = i / (K / 8), kk = (i % (K / 8)) * 8;
      size_t grow = (size_t)mtile * 128 + r;
      uint4 v = *(const uint4*)(A + grow * K + kk);
      *(uint4*)&As[r][kk] = v;
    }
  } else {
    const float* A = (const float*)Aptr;
    for (int i = tid; i < 128 * (K / 4); i += 256) {
      int r = i / (K / 4), kk = (i % (K / 4)) * 4;
      int grow = mtile * 128 + r;
      int bb = grow >> tcShift, tt = grow & tcMask;
      const float* p = A + (size_t)bb * bStride + (size_t)tt * K + kk;
      float4 v = *(const float4*)p;
      uint2 u;
      u.x = pack2(v.x, v.y);
      u.y = pack2(v.z, v.w);
      *(uint2*)&As[r][kk] = u;
    }
  }
  for (int i = tid; i < 64 * (K / 4); i += 256) {
    int r = i / (K / 4), kk = (i % (K / 4)) * 4;
    const float* p = W + (size_t)(ntile * 64 + r) * K + kk;
    float4 v = *(const float4*)p;
    uint2 u;
    u.x = pack2(v.x, v.y);
    u.y = pack2(v.z, v.w);
    *(uint2*)&Bs[r][kk] = u;
  }
  __syncthreads();

  const int w = tid >> 6, l = tid & 63;
  const int lr = l & 15, lg = l >> 4;
  f32x4 acc[2][4] = {};
#pragma unroll
  for (int ks = 0; ks < K / 32; ++ks) {
    f16x8 a0 = *(const f16x8*)&As[w * 32 + lr][ks * 32 + lg * 8];
    f16x8 a1 = *(const f16x8*)&As[w * 32 + 16 + lr][ks * 32 + lg * 8];
    f16x8 bf[4];
#pragma unroll
    for (int nj = 0; nj < 4; ++nj)
      bf[nj] = *(const f16x8*)&Bs[nj * 16 + lr][ks * 32 + lg * 8];
#pragma unroll
    for (int nj = 0; nj < 4; ++nj) {
      acc[0][nj] = __builtin_amdgcn_mfma_f32_16x16x32_f16(a0, bf[nj], acc[0][nj], 0, 0, 0);
      acc[1][nj] = __builtin_amdgcn_mfma_f32_16x16x32_f16(a1, bf[nj], acc[1][nj], 0, 0, 0);
    }
  }
  // C/D layout (verified m89, dtype-independent): col = lane&15, row = (lane>>4)*4+q
#pragma unroll
  for (int mi = 0; mi < 2; ++mi) {
#pragma unroll
    for (int nj = 0; nj < 4; ++nj) {
      int col = ntile * 64 + nj * 16 + lr;
#pragma unroll
      for (int q = 0; q < 4; ++q) {
        size_t grow = (size_t)mtile * 128 + w * 32 + mi * 16 + lg * 4 + q;
        D[grow * NG + col] = (f16)acc[mi][nj][q];
      }
    }
  }
}

// ======================= Recurrence (one layer, one T-chunk) ==============
__global__ __launch_bounds__(512) void lstm_rec(
    const f16* __restrict__ Gx,     // [B][Tc][512]  x-side gate pre-acts
    const float* __restrict__ Whh,  // [512][128]
    const float* __restrict__ bih, const float* __restrict__ bhh,
    const float* __restrict__ hin,  // [B][128] f32 (h0 slice or state)
    const float* __restrict__ cin,  // [B][128] f32
    float* __restrict__ hstate, float* __restrict__ cstate,  // [B][128] f32
    f16* __restrict__ h1out,        // [B][Tc][128] or null (layer 0 only)
    float* __restrict__ finalOut,   // [B][128] or null (last chunk layer 1)
    int Tc) {
  const int b = blockIdx.x, tid = threadIdx.x;
  const int c = tid >> 2, s = tid & 3;  // cell, K-chunk
  __shared__ unsigned hbuf[2][64];      // h_{t-1} as f16 pairs, double-buffered

  // W_hh rows for all 4 gates of cell c, pairs [16s, 16s+16)
  unsigned wh[4][16];
  float bias[4];
#pragma unroll
  for (int g = 0; g < 4; ++g) {
    const int r = g * HID + c;
#pragma unroll
    for (int j = 0; j < 16; ++j) {
      int p = 16 * s + j;
      wh[g][j] = pack2(Whh[(size_t)r * HID + 2 * p], Whh[(size_t)r * HID + 2 * p + 1]);
    }
    bias[g] = bih[r] + bhh[r];
  }
  float cst = cin[b * HID + c];
  if (tid < 64) hbuf[0][tid] = pack2(hin[b * HID + 2 * tid], hin[b * HID + 2 * tid + 1]);

  const f16* gxb = Gx + (size_t)b * Tc * NG;
  f16 gxc[4], gxn[4];
#pragma unroll
  for (int g = 0; g < 4; ++g) gxc[g] = gxb[g * HID + c];
  __syncthreads();

  float h = 0.f;
#pragma unroll 1
  for (int t = 0; t < Tc; ++t) {
    if (t + 1 < Tc) {  // prefetch next step's x-side pre-acts (L2/L3-resident)
#pragma unroll
      for (int g = 0; g < 4; ++g) gxn[g] = gxb[(size_t)(t + 1) * NG + g * HID + c];
    }
    const uint4* hs = (const uint4*)&hbuf[t & 1][16 * s];
    float ai = 0.f, af = 0.f, ag = 0.f, ao = 0.f;
#pragma unroll
    for (int k = 0; k < 4; ++k) {
      uint4 v = hs[k];
      ai = dot2f(v.x, wh[0][4 * k + 0], ai); ai = dot2f(v.y, wh[0][4 * k + 1], ai);
      ai = dot2f(v.z, wh[0][4 * k + 2], ai); ai = dot2f(v.w, wh[0][4 * k + 3], ai);
      af = dot2f(v.x, wh[1][4 * k + 0], af); af = dot2f(v.y, wh[1][4 * k + 1], af);
      af = dot2f(v.z, wh[1][4 * k + 2], af); af = dot2f(v.w, wh[1][4 * k + 3], af);
      ag = dot2f(v.x, wh[2][4 * k + 0], ag); ag = dot2f(v.y, wh[2][4 * k + 1], ag);
      ag = dot2f(v.z, wh[2][4 * k + 2], ag); ag = dot2f(v.w, wh[2][4 * k + 3], ag);
      ao = dot2f(v.x, wh[3][4 * k + 0], ao); ao = dot2f(v.y, wh[3][4 * k + 1], ao);
      ao = dot2f(v.z, wh[3][4 * k + 2], ao); ao = dot2f(v.w, wh[3][4 * k + 3], ao);
    }
    // quad butterfly: all 4 s-lanes get the full K-sums
    ai = qp_add<0xB1>(ai); ai = qp_add<0x4E>(ai);
    af = qp_add<0xB1>(af); af = qp_add<0x4E>(af);
    ag = qp_add<0xB1>(ag); ag = qp_add<0x4E>(ag);
    ao = qp_add<0xB1>(ao); ao = qp_add<0x4E>(ao);

    float iv = sigm(ai + bias[0] + (float)gxc[0]);
    float fv = sigm(af + bias[1] + (float)gxc[1]);
    float gv = tanh_f(ag + bias[2] + (float)gxc[2]);
    float ov = sigm(ao + bias[3] + (float)gxc[3]);
    cst = fv * cst + iv * gv;
    h = ov * tanh_f(cst);
    f16 hf = (f16)h;
    if (s == 0) {
      ((f16*)&hbuf[(t + 1) & 1][0])[c] = hf;
      if (h1out) h1out[((size_t)b * Tc + t) * HID + c] = hf;
    }
    __syncthreads();
#pragma unroll
    for (int g = 0; g < 4; ++g) gxc[g] = gxn[g];
  }
  if (s == 0) {
    hstate[b * HID + c] = (float)(f16)h;  // chunk-chain uses f16-rounded h
    cstate[b * HID + c] = cst;
    if (finalOut) finalOut[b * HID + c] = h;
  }
}

extern "C" void kernel_launch(void* const* d_in, const int* in_sizes, int n_in,
                              void* d_out, int out_size, void* d_ws,
                              size_t ws_size, hipStream_t stream) {
  const float* x    = (const float*)d_in[0];
  const float* h0   = (const float*)d_in[1];
  const float* c0   = (const float*)d_in[2];
  const float* Wih0 = (const float*)d_in[3];
  const float* Whh0 = (const float*)d_in[4];
  const float* bih0 = (const float*)d_in[5];
  const float* bhh0 = (const float*)d_in[6];
  const float* Wih1 = (const float*)d_in[7];
  const float* Whh1 = (const float*)d_in[8];
  const float* bih1 = (const float*)d_in[9];
  const float* bhh1 = (const float*)d_in[10];

  // choose fewest chunks NC such that ws fits (NC=8 needs 21.8MB; 33.5MB proven)
  int NC = 16;
  for (int n = 1; n <= 16; n *= 2) {
    size_t tc = T_ / n;
    size_t need = (size_t)B_ * tc * NG * 2   // Gx chunk f16
                + (size_t)B_ * tc * HID * 2  // h1 chunk f16
                + 4 * (size_t)B_ * HID * 4   // h,c state x 2 layers
                + 256;
    if (need <= ws_size) { NC = n; break; }
  }
  const int Tc = T_ / NC;
  int tcShift = 0;
  while ((1 << tcShift) < Tc) ++tcShift;

  char* w = (char*)d_ws;
  f16* Gx = (f16*)w;        w += (size_t)B_ * Tc * NG * 2;
  f16* h1 = (f16*)w;        w += (size_t)B_ * Tc * HID * 2;
  float* sH0 = (float*)w;   w += (size_t)B_ * HID * 4;
  float* sC0 = (float*)w;   w += (size_t)B_ * HID * 4;
  float* sH1 = (float*)w;   w += (size_t)B_ * HID * 4;
  float* sC1 = (float*)w;

  const dim3 ggrid(2 * Tc, 8);  // (B_*Tc/128, NG/64)
  for (int cc = 0; cc < NC; ++cc) {
    // layer 0: x-side GEMM for this chunk, then recurrence
    gemm_xw<KX0, false><<<ggrid, 256, 0, stream>>>(
        x + (size_t)cc * Tc * KX0, (size_t)T_ * KX0, tcShift, Tc - 1, Wih0, Gx);
    lstm_rec<<<B_, 512, 0, stream>>>(
        Gx, Whh0, bih0, bhh0,
        cc == 0 ? h0 : sH0, cc == 0 ? c0 : sC0, sH0, sC0,
        h1, nullptr, Tc);
    // layer 1: h1-side GEMM (A = contiguous f16 chunk), then recurrence
    gemm_xw<HID, true><<<ggrid, 256, 0, stream>>>(
        h1, 0, tcShift, Tc - 1, Wih1, Gx);
    lstm_rec<<<B_, 512, 0, stream>>>(
        Gx, Whh1, bih1, bhh1,
        cc == 0 ? h0 + B_ * HID : sH1, cc == 0 ? c0 + B_ * HID : sC1, sH1, sC1,
        nullptr, cc == NC - 1 ? (float*)d_out : nullptr, Tc);
  }
}

// Round 9
// 899.247 us; speedup vs baseline: 1.2341x; 1.2341x over previous
//
#include <hip/hip_runtime.h>

// OnsetLSTM: 2-layer LSTM, B=256, T=512, D=160, H=128, fp32 in/out.
//
// Architecture (R8, kept): x-side gate pre-acts via MFMA GEMM; recurrence
// keeps only W_hh in regs (64 pairs/thread at 512thr -> no spill under the
// 65536-VGPR/workgroup cap hipcc enforces).
//
// R8->R9 fixes (rec was 455us/layer, ~2130cy/step, latency-structural):
//  1. Gx stored TRANSPOSED [(b*128+cell)*4+gate][t]: rec prefetches 8 steps
//     per gate with ONE dwordx4, double-buffered in regs -> vmcnt!=0 at only
//     1 of 8 barriers (hipcc drains vmcnt(0) before every s_barrier).
//  2. h1 store issued at the TOP of the next step -> ack retires before the
//     barrier drain instead of stalling it.
//  3. Chunked layer pipeline (NC=4, Tc=128): one dispatch runs L0 chunk c
//     AND L1 chunk c-1 as 512 blocks -> 2 blocks/CU, two independent
//     recurrences hide each other's latency. 640 step-times vs 1024 serial.

typedef _Float16 f16;
typedef _Float16 f16x8 __attribute__((ext_vector_type(8)));
typedef float f32x4 __attribute__((ext_vector_type(4)));
typedef _Float16 half2_t __attribute__((ext_vector_type(2)));

#define B_  256
#define T_  512
#define HID 128
#define NG  512
#define KX0 160
#define NC  4
#define TC  128   // T_/NC

static __device__ __forceinline__ unsigned pack2(float a, float b) {
  union { f16 h[2]; unsigned u; } v;
  v.h[0] = (f16)a; v.h[1] = (f16)b;
  return v.u;
}

static __device__ __forceinline__ float dot2f(unsigned a, unsigned b, float c) {
#if __has_builtin(__builtin_amdgcn_fdot2)
  return __builtin_amdgcn_fdot2(__builtin_bit_cast(half2_t, a),
                                __builtin_bit_cast(half2_t, b), c, false);
#else
  half2_t x = __builtin_bit_cast(half2_t, a);
  half2_t y = __builtin_bit_cast(half2_t, b);
  float r = c;
  r = fmaf((float)x[0], (float)y[0], r);
  r = fmaf((float)x[1], (float)y[1], r);
  return r;
#endif
}

static __device__ __forceinline__ float fast_rcp(float x) {
#if __has_builtin(__builtin_amdgcn_rcpf)
  return __builtin_amdgcn_rcpf(x);
#else
  return 1.0f / x;
#endif
}
static __device__ __forceinline__ float fast_exp2(float x) {
#if __has_builtin(__builtin_amdgcn_exp2f)
  return __builtin_amdgcn_exp2f(x);
#else
  return exp2f(x);
#endif
}
static __device__ __forceinline__ float sigm(float x) {
  return fast_rcp(1.0f + fast_exp2(x * -1.44269504f));
}
static __device__ __forceinline__ float tanh_f(float x) {
  float e = fast_exp2(x * 2.885390082f);
  return 1.0f - 2.0f * fast_rcp(e + 1.0f);
}

template <int CTRL>
static __device__ __forceinline__ float qp_add(float v) {
  int iv = __builtin_bit_cast(int, v);
  int t = __builtin_amdgcn_update_dpp(iv, iv, CTRL, 0xF, 0xF, true);
  return v + __builtin_bit_cast(float, t);
}

// extract f16 #j (j compile-time after unroll) from an 8-half batch
static __device__ __forceinline__ float gxval(const uint4& g, int j) {
  unsigned w = (j >> 1) == 0 ? g.x : (j >> 1) == 1 ? g.y : (j >> 1) == 2 ? g.z : g.w;
  unsigned hs = (j & 1) ? (w >> 16) : (w & 0xffffu);
  f16 v = __builtin_bit_cast(f16, (unsigned short)hs);
  return (float)v;
}

// ======================= GEMM: Gx = A @ W^T, transposed-t store =============
// A: [B][Tc][K] (f32 strided x, or f16 contiguous h1). W: [512][K] f32.
// D layout: [(b*128 + cell)*4 + gate][t], t in [0,TC).
template <int K, bool AF16>
__global__ __launch_bounds__(256) void gemm_xw(
    const void* __restrict__ Aptr, size_t bStride,
    const float* __restrict__ W, f16* __restrict__ D) {
  constexpr int KP = K + 8;
  __shared__ f16 As[128][KP];
  __shared__ f16 Bs[64][KP];
  const int tid = threadIdx.x;
  const int mtile = blockIdx.x, ntile = blockIdx.y;

  if (AF16) {
    const f16* A = (const f16*)Aptr;
    for (int i = tid; i < 128 * (K / 8); i += 256) {
      int r = i / (K / 8), kk = (i % (K / 8)) * 8;
      size_t grow = (size_t)mtile * 128 + r;
      uint4 v = *(const uint4*)(A + grow * K + kk);
      *(uint4*)&As[r][kk] = v;
    }
  } else {
    const float* A = (const float*)Aptr;
    for (int i = tid; i < 128 * (K / 4); i += 256) {
      int r = i / (K / 4), kk = (i % (K / 4)) * 4;
      int grow = mtile * 128 + r;
      int bb = grow >> 7, tt = grow & (TC - 1);
      const float* p = A + (size_t)bb * bStride + (size_t)tt * K + kk;
      float4 v = *(const float4*)p;
      uint2 u;
      u.x = pack2(v.x, v.y);
      u.y = pack2(v.z, v.w);
      *(uint2*)&As[r][kk] = u;
    }
  }
  for (int i = tid; i < 64 * (K / 4); i += 256) {
    int r = i / (K / 4), kk = (i % (K / 4)) * 4;
    const float* p = W + (size_t)(ntile * 64 + r) * K + kk;
    float4 v = *(const float4*)p;
    uint2 u;
    u.x = pack2(v.x, v.y);
    u.y = pack2(v.z, v.w);
    *(uint2*)&Bs[r][kk] = u;
  }
  __syncthreads();

  const int w = tid >> 6, l = tid & 63;
  const int lr = l & 15, lg = l >> 4;
  f32x4 acc[2][4] = {};
#pragma unroll
  for (int ks = 0; ks < K / 32; ++ks) {
    f16x8 a0 = *(const f16x8*)&As[w * 32 + lr][ks * 32 + lg * 8];
    f16x8 a1 = *(const f16x8*)&As[w * 32 + 16 + lr][ks * 32 + lg * 8];
    f16x8 bf[4];
#pragma unroll
    for (int nj = 0; nj < 4; ++nj)
      bf[nj] = *(const f16x8*)&Bs[nj * 16 + lr][ks * 32 + lg * 8];
#pragma unroll
    for (int nj = 0; nj < 4; ++nj) {
      acc[0][nj] = __builtin_amdgcn_mfma_f32_16x16x32_f16(a0, bf[nj], acc[0][nj], 0, 0, 0);
      acc[1][nj] = __builtin_amdgcn_mfma_f32_16x16x32_f16(a1, bf[nj], acc[1][nj], 0, 0, 0);
    }
  }
  // C/D layout (m89): col = lane&15, row = (lane>>4)*4 + q. Rows are t -> the
  // 4 q's are 4 consecutive t of the same (b, col): pack into one 8B store.
#pragma unroll
  for (int mi = 0; mi < 2; ++mi) {
#pragma unroll
    for (int nj = 0; nj < 4; ++nj) {
      int col = ntile * 64 + nj * 16 + lr;
      int cell = col & 127, gate = col >> 7;
      int rowbase = mtile * 128 + w * 32 + mi * 16 + lg * 4;
      int bb = rowbase >> 7, tt = rowbase & (TC - 1);
      unsigned lo = pack2(acc[mi][nj][0], acc[mi][nj][1]);
      unsigned hi = pack2(acc[mi][nj][2], acc[mi][nj][3]);
      size_t idx = (((size_t)bb * HID + cell) * 4 + gate) * TC + tt;
      uint2 u; u.x = lo; u.y = hi;
      *(uint2*)(D + idx) = u;
    }
  }
}

// ======================= Recurrence (chunk, possibly 2 layers) ==============
struct RecArgs {
  const f16* Gx;      // [(b*128+cell)*4+gate][TC]
  const float* Whh;   // [512][128]
  const float* bih; const float* bhh;
  const float* hin; const float* cin;   // [B][128] f32
  float* hst; float* cst;               // [B][128] f32
  f16* h1out;                            // [B][TC][128] or null
  float* fin;                            // [B][128] or null
};

__global__ __launch_bounds__(512) void lstm_rec2(RecArgs A, RecArgs B, int nA) {
  const RecArgs& P = ((int)blockIdx.x < nA) ? A : B;
  const int b = ((int)blockIdx.x < nA) ? blockIdx.x : blockIdx.x - nA;
  const int tid = threadIdx.x;
  const int c = tid >> 2, s = tid & 3;
  __shared__ unsigned hbuf[2][64];

  unsigned wh[4][16];
  float bias[4];
#pragma unroll
  for (int g = 0; g < 4; ++g) {
    const int r = g * HID + c;
#pragma unroll
    for (int j = 0; j < 16; ++j) {
      int p = 16 * s + j;
      wh[g][j] = pack2(P.Whh[(size_t)r * HID + 2 * p], P.Whh[(size_t)r * HID + 2 * p + 1]);
    }
    bias[g] = P.bih[r] + P.bhh[r];
  }
  float cstate = P.cin[b * HID + c];
  if (tid < 64)
    hbuf[0][tid] = pack2(P.hin[b * HID + 2 * tid], P.hin[b * HID + 2 * tid + 1]);

  const f16* gxb = P.Gx + ((size_t)b * HID + c) * 4 * TC;
  f16* h1x = P.h1out ? P.h1out + (size_t)b * TC * HID + c : (f16*)nullptr;

  uint4 gA[4], gB[4];
#pragma unroll
  for (int g = 0; g < 4; ++g) gA[g] = *(const uint4*)(gxb + (size_t)g * TC + 0);
  __syncthreads();

  float hprev = 0.f;

  auto STEP = [&](const uint4 (&gx)[4], int t, int j) {
    // early store of previous step's h1 (ack retires before this step's barrier)
    if (h1x && s == 0 && t > 0) h1x[(size_t)(t - 1) * HID] = (f16)hprev;
    const uint4* hs4 = (const uint4*)&hbuf[t & 1][16 * s];
    float ai = 0.f, af = 0.f, ag = 0.f, ao = 0.f;
#pragma unroll
    for (int k = 0; k < 4; ++k) {
      uint4 v = hs4[k];
      ai = dot2f(v.x, wh[0][4 * k + 0], ai); ai = dot2f(v.y, wh[0][4 * k + 1], ai);
      ai = dot2f(v.z, wh[0][4 * k + 2], ai); ai = dot2f(v.w, wh[0][4 * k + 3], ai);
      af = dot2f(v.x, wh[1][4 * k + 0], af); af = dot2f(v.y, wh[1][4 * k + 1], af);
      af = dot2f(v.z, wh[1][4 * k + 2], af); af = dot2f(v.w, wh[1][4 * k + 3], af);
      ag = dot2f(v.x, wh[2][4 * k + 0], ag); ag = dot2f(v.y, wh[2][4 * k + 1], ag);
      ag = dot2f(v.z, wh[2][4 * k + 2], ag); ag = dot2f(v.w, wh[2][4 * k + 3], ag);
      ao = dot2f(v.x, wh[3][4 * k + 0], ao); ao = dot2f(v.y, wh[3][4 * k + 1], ao);
      ao = dot2f(v.z, wh[3][4 * k + 2], ao); ao = dot2f(v.w, wh[3][4 * k + 3], ao);
    }
    ai = qp_add<0xB1>(ai); ai = qp_add<0x4E>(ai);
    af = qp_add<0xB1>(af); af = qp_add<0x4E>(af);
    ag = qp_add<0xB1>(ag); ag = qp_add<0x4E>(ag);
    ao = qp_add<0xB1>(ao); ao = qp_add<0x4E>(ao);

    float iv = sigm(ai + bias[0] + gxval(gx[0], j));
    float fv = sigm(af + bias[1] + gxval(gx[1], j));
    float gv = tanh_f(ag + bias[2] + gxval(gx[2], j));
    float ov = sigm(ao + bias[3] + gxval(gx[3], j));
    cstate = fv * cstate + iv * gv;
    float h = ov * tanh_f(cstate);
    if (s == 0) ((f16*)&hbuf[(t + 1) & 1][0])[c] = (f16)h;
    hprev = h;
    __syncthreads();
  };

#pragma unroll 1
  for (int t0 = 0; t0 < TC; t0 += 16) {
    {
      int tn = t0 + 8;
#pragma unroll
      for (int g = 0; g < 4; ++g) gB[g] = *(const uint4*)(gxb + (size_t)g * TC + tn);
    }
#pragma unroll
    for (int j = 0; j < 8; ++j) STEP(gA, t0 + j, j);
    {
      int tm = t0 + 16; if (tm > TC - 8) tm = TC - 8;  // clamp (values unused)
#pragma unroll
      for (int g = 0; g < 4; ++g) gA[g] = *(const uint4*)(gxb + (size_t)g * TC + tm);
    }
#pragma unroll
    for (int j = 0; j < 8; ++j) STEP(gB, t0 + 8 + j, j);
  }

  if (h1x && s == 0) h1x[(size_t)(TC - 1) * HID] = (f16)hprev;
  if (s == 0) {
    P.hst[b * HID + c] = (float)(f16)hprev;  // chunk chain uses f16-rounded h
    P.cst[b * HID + c] = cstate;
    if (P.fin) P.fin[b * HID + c] = hprev;
  }
}

extern "C" void kernel_launch(void* const* d_in, const int* in_sizes, int n_in,
                              void* d_out, int out_size, void* d_ws,
                              size_t ws_size, hipStream_t stream) {
  const float* x    = (const float*)d_in[0];
  const float* h0   = (const float*)d_in[1];
  const float* c0   = (const float*)d_in[2];
  const float* Wih0 = (const float*)d_in[3];
  const float* Whh0 = (const float*)d_in[4];
  const float* bih0 = (const float*)d_in[5];
  const float* bhh0 = (const float*)d_in[6];
  const float* Wih1 = (const float*)d_in[7];
  const float* Whh1 = (const float*)d_in[8];
  const float* bih1 = (const float*)d_in[9];
  const float* bhh1 = (const float*)d_in[10];

  char* w = (char*)d_ws;
  f16* Gx0 = (f16*)w;      w += (size_t)B_ * TC * NG * 2;   // 33.5 MB
  f16* Gx1 = (f16*)w;      w += (size_t)B_ * TC * NG * 2;   // 33.5 MB
  f16* h1  = (f16*)w;      w += (size_t)B_ * TC * HID * 2;  // 8.4 MB
  float* sH0 = (float*)w;  w += (size_t)B_ * HID * 4;
  float* sC0 = (float*)w;  w += (size_t)B_ * HID * 4;
  float* sH1 = (float*)w;  w += (size_t)B_ * HID * 4;
  float* sC1 = (float*)w;

  const dim3 ggrid(B_ * TC / 128, 8);  // (256, 8)

  auto l0args = [&](int cc) {
    RecArgs a;
    a.Gx = Gx0; a.Whh = Whh0; a.bih = bih0; a.bhh = bhh0;
    a.hin = cc == 0 ? h0 : sH0; a.cin = cc == 0 ? c0 : sC0;
    a.hst = sH0; a.cst = sC0; a.h1out = h1; a.fin = nullptr;
    return a;
  };
  auto l1args = [&](int cc) {
    RecArgs a;
    a.Gx = Gx1; a.Whh = Whh1; a.bih = bih1; a.bhh = bhh1;
    a.hin = cc == 0 ? h0 + B_ * HID : sH1; a.cin = cc == 0 ? c0 + B_ * HID : sC1;
    a.hst = sH1; a.cst = sC1; a.h1out = nullptr;
    a.fin = cc == NC - 1 ? (float*)d_out : nullptr;
    return a;
  };

  RecArgs dummy = {};

  // chunk 0, layer 0
  gemm_xw<KX0, false><<<ggrid, 256, 0, stream>>>(
      x + (size_t)0 * TC * KX0, (size_t)T_ * KX0, Wih0, Gx0);
  lstm_rec2<<<B_, 512, 0, stream>>>(l0args(0), dummy, B_);

  for (int cc = 1; cc < NC; ++cc) {
    // x-side GEMMs for the upcoming pair: L1 uses h1(cc-1), L0 uses x(cc)
    gemm_xw<HID, true><<<ggrid, 256, 0, stream>>>(h1, 0, Wih1, Gx1);
    gemm_xw<KX0, false><<<ggrid, 256, 0, stream>>>(
        x + (size_t)cc * TC * KX0, (size_t)T_ * KX0, Wih0, Gx0);
    // L0 chunk cc  ||  L1 chunk cc-1  (512 blocks -> 2/CU)
    lstm_rec2<<<2 * B_, 512, 0, stream>>>(l0args(cc), l1args(cc - 1), B_);
  }

  // tail: layer 1, last chunk
  gemm_xw<HID, true><<<ggrid, 256, 0, stream>>>(h1, 0, Wih1, Gx1);
  lstm_rec2<<<B_, 512, 0, stream>>>(l1args(NC - 1), dummy, B_);
}